// Round 6
// baseline (88.091 us; speedup 1.0000x reference)
//
#include <hip/hip_runtime.h>
#include <stdint.h>

#define NN 2048
#define KK 20
#define NSLICE 8   // L*B = 2*4

typedef float vfloat4 __attribute__((ext_vector_type(4)));

// Wave-wide max of a nonnegative int, result broadcast (SGPR). Pure VALU DPP.
__device__ __forceinline__ int wave_max_i32(int v) {
    int t;
    t = __builtin_amdgcn_update_dpp(0, v, 0x111, 0xf, 0xf, true);  // row_shr:1
    v = (v > t) ? v : t;
    t = __builtin_amdgcn_update_dpp(0, v, 0x112, 0xf, 0xf, true);  // row_shr:2
    v = (v > t) ? v : t;
    t = __builtin_amdgcn_update_dpp(0, v, 0x114, 0xf, 0xf, true);  // row_shr:4
    v = (v > t) ? v : t;
    t = __builtin_amdgcn_update_dpp(0, v, 0x118, 0xf, 0xf, true);  // row_shr:8
    v = (v > t) ? v : t;
    t = __builtin_amdgcn_update_dpp(v, v, 0x142, 0xa, 0xf, false); // row_bcast:15
    v = (v > t) ? v : t;
    t = __builtin_amdgcn_update_dpp(v, v, 0x143, 0xc, 0xf, false); // row_bcast:31
    v = (v > t) ? v : t;
    return __builtin_amdgcn_readlane(v, 63);
}

// Branch-free insert of k into sorted (m1 >= m2 >= m3), 64-bit keys.
__device__ __forceinline__ void insert3(unsigned long long k,
    unsigned long long& m1, unsigned long long& m2, unsigned long long& m3) {
    const bool c1 = k > m1, c2 = k > m2, c3 = k > m3;
    m3 = c3 ? (c2 ? m2 : k) : m3;   // uses old m2
    m2 = c2 ? (c1 ? m1 : k) : m2;   // uses old m1
    m1 = c1 ? k : m1;
}

// Exact ordered top-20 extraction from per-lane cached top-3 (+rare rescan).
// Returns this lane's rank-`lane` winner column (valid for lane < KK).
__device__ __forceinline__ unsigned int extract20(
    const float sc[32], unsigned long long m1, unsigned long long m2,
    unsigned long long m3, int lane, int lane4)
{
    int cnt = 3;
    unsigned int removed = 0;
    unsigned int mycol = 0;
    #pragma clang loop unroll(disable)
    for (int pass = 0; pass < KK; ++pass) {
        const int hs = (int)(unsigned int)(m1 >> 32);     // score bits (>=0)
        const int smax = wave_max_i32(hs);                // global max score
        const bool tied = (hs == smax);
        const unsigned long long ball = __ballot(tied);
        unsigned int col;
        bool iwin;
        if (__popcll(ball) == 1) {
            // fast path: unique score owner -- no tie-break reduce needed
            const int wl = __ffsll((long long)ball) - 1;  // SGPR-uniform lane
            const unsigned int wlo = (unsigned int)
                __builtin_amdgcn_readlane((int)(unsigned int)m1, wl);
            col = (NN - 1) - wlo;
            iwin = (lane == wl);
        } else {
            // exact tie on score bits across lanes: pick smallest col
            const int lo = tied ? (int)(unsigned int)m1 : 0;  // 2047-col
            const int tmax = wave_max_i32(lo);
            col = (NN - 1) - (unsigned int)tmax;
            iwin = tied && ((int)(unsigned int)m1 == tmax);
        }
        if (lane == pass) mycol = col;
        if (iwin) {
            const int slot = ((col >> 8) << 2) | (col & 3);
            removed |= (1u << slot);
            m1 = m2; m2 = m3; m3 = 0ull;
            if (--cnt == 0) {
                // rare (~0.3/row): rebuild top-3 of non-removed elements
                m1 = 0ull; m2 = 0ull; m3 = 0ull;
                #pragma unroll
                for (int ss = 0; ss < 32; ++ss) {
                    if (!((removed >> ss) & 1u)) {
                        const int c2 = ((ss >> 2) << 8) + lane4 + (ss & 3);
                        unsigned long long k =
                            ((unsigned long long)__float_as_uint(sc[ss]) << 32) |
                            (unsigned int)(NN - 1 - c2);
                        insert3(k, m1, m2, m3);
                    }
                }
                cnt = 3;
            }
        }
    }
    return mycol;
}

// Issue all 16 row loads via volatile asm (cannot be sunk/reordered).
#define ISSUE_ROW(arow_, nrow_) do {                                         \
    _Pragma("unroll")                                                        \
    for (int t = 0; t < 8; ++t) {                                            \
        asm volatile("global_load_dwordx4 %0, %1, off"                       \
                     : "=v"(av[t]) : "v"((arow_) + t * 256 + lane4));        \
        asm volatile("global_load_dwordx4 %0, %1, off"                       \
                     : "=v"(nv[t]) : "v"((nrow_) + t * 256 + lane4));        \
    }                                                                        \
    __builtin_amdgcn_sched_barrier(0);                                       \
} while (0)

// Consume one tile under a counted vmcnt. Entries in the vm FIFO issued
// after this tile's load pair: (16-2(t+1)) younger loads + t stores = 14-t.
// Older entries (incl. previous row's stores) only tighten the wait.
#define TILE(t, vm, orow_) do {                                              \
    asm volatile("s_waitcnt vmcnt(" #vm ")" ::: "memory");                   \
    __builtin_amdgcn_sched_barrier(0);                                       \
    const int col = (t) * 256 + lane4;                                       \
    vfloat4 ov = av[t] * 1e-7f;                                              \
    __builtin_nontemporal_store(ov, reinterpret_cast<vfloat4*>((orow_) + col)); \
    float s[4];                                                              \
    {                                                                        \
        _Pragma("clang fp contract(off)")                                    \
        s[0] = fabsf(av[t].x) + nv[t].x * 0.01f;                             \
        s[1] = fabsf(av[t].y) + nv[t].y * 0.01f;                             \
        s[2] = fabsf(av[t].z) + nv[t].z * 0.01f;                             \
        s[3] = fabsf(av[t].w) + nv[t].w * 0.01f;                             \
    }                                                                        \
    _Pragma("unroll")                                                        \
    for (int c = 0; c < 4; ++c) {                                            \
        sc[(t) * 4 + c] = s[c];                                              \
        unsigned long long k =                                               \
            ((unsigned long long)__float_as_uint(s[c]) << 32) |              \
            (unsigned int)(NN - 1 - (col + c));                              \
        insert3(k, m1, m2, m3);                                              \
    }                                                                        \
} while (0)

#define CONSUME_ROW(orow_)                                                   \
    TILE(0, 14, orow_); TILE(1, 13, orow_); TILE(2, 12, orow_);              \
    TILE(3, 11, orow_); TILE(4, 10, orow_); TILE(5,  9, orow_);              \
    TILE(6,  8, orow_); TILE(7,  7, orow_)

// Kernel 1: one wave handles TWO rows (g and g+8192), software-pipelined:
// row-B's 16 loads are issued before row-A's extraction, so the serial
// extraction phase is covered by in-flight memory. Writes base out = adj*EPS
// (non-temporal) and winners[slice][row][rank] = col for both rows at end.
__global__ __launch_bounds__(256) void mask_topk_rows(
    const float* __restrict__ adj, const float* __restrict__ noise,
    float* __restrict__ out, unsigned short* __restrict__ winners)
{
    const int lane  = threadIdx.x & 63;
    const int wave  = threadIdx.x >> 6;
    const int lane4 = lane << 2;

    const int rowA_g = (blockIdx.x << 2) + wave;     // 0..8191
    const int rowB_g = rowA_g + 8192;                // 8192..16383

    const size_t baseA = ((size_t)(rowA_g >> 11) * NN + (rowA_g & (NN - 1))) * NN;
    const size_t baseB = ((size_t)(rowB_g >> 11) * NN + (rowB_g & (NN - 1))) * NN;
    const float* __restrict__ arowA = adj + baseA;
    const float* __restrict__ nrowA = noise + baseA;
    float* __restrict__ orowA = out + baseA;
    const float* __restrict__ arowB = adj + baseB;
    const float* __restrict__ nrowB = noise + baseB;
    float* __restrict__ orowB = out + baseB;

    vfloat4 av[8], nv[8];
    float sc[32];
    unsigned long long m1, m2, m3;

    // ---- Row A: issue + consume ----
    ISSUE_ROW(arowA, nrowA);
    m1 = 0ull; m2 = 0ull; m3 = 0ull;
    CONSUME_ROW(orowA);

    // ---- Row B: issue loads NOW, before A's extraction ----
    ISSUE_ROW(arowB, nrowB);

    // ---- Extract A while B's loads are in flight ----
    const unsigned int mycolA = extract20(sc, m1, m2, m3, lane, lane4);

    // ---- Row B: consume + extract ----
    m1 = 0ull; m2 = 0ull; m3 = 0ull;
    CONSUME_ROW(orowB);
    const unsigned int mycolB = extract20(sc, m1, m2, m3, lane, lane4);

    if (lane < KK) {
        winners[(size_t)rowA_g * KK + lane] = (unsigned short)mycolA;
        winners[(size_t)rowB_g * KK + lane] = (unsigned short)mycolB;
    }
}

// Kernel 2: for each (slice,row,rank): col = winners[...];
// out[slice][col][rank] = adj*(1+EPS). Duplicate (col,rank) across rows
// write identical values -> benign race.
__global__ __launch_bounds__(256) void mask_boost(
    const float* __restrict__ adj, float* __restrict__ out,
    const unsigned short* __restrict__ winners)
{
    const int idx = blockIdx.x * 256 + threadIdx.x;
    if (idx >= NSLICE * NN * KK) return;
    const int rank  = idx % KK;
    const int slice = idx / (KK * NN);
    const int col = winners[idx];
    const size_t off = ((size_t)slice * NN + col) * NN + rank;
    out[off] = adj[off] * (1.0f + 1e-7f);
}

extern "C" void kernel_launch(void* const* d_in, const int* in_sizes, int n_in,
                              void* d_out, int out_size, void* d_ws, size_t ws_size,
                              hipStream_t stream) {
    const float* adj   = (const float*)d_in[0];
    const float* noise = (const float*)d_in[1];
    float* out = (float*)d_out;
    unsigned short* winners = (unsigned short*)d_ws;  // 16384*20*2B = 640 KiB

    // 2048 blocks x 4 waves; each wave pipelines rows g and g+8192.
    mask_topk_rows<<<2048, 256, 0, stream>>>(adj, noise, out, winners);

    const int total = NSLICE * NN * KK;           // 327,680
    mask_boost<<<(total + 255) / 256, 0x100, 0, stream>>>(adj, out, winners);
}

// Round 8
// 77.980 us; speedup vs baseline: 1.1297x; 1.1297x over previous
//
#include <hip/hip_runtime.h>
#include <stdint.h>

#define NN 2048
#define KK 20
#define NSLICE 8   // L*B = 2*4
#define NROWS (NSLICE * NN)        // 16384
#define NBOOST (NSLICE * NN * KK)  // 327680

typedef float vfloat4 __attribute__((ext_vector_type(4)));

// Wave-wide max of a nonnegative int, result broadcast (SGPR). Pure VALU DPP.
__device__ __forceinline__ int wave_max_i32(int v) {
    int t;
    t = __builtin_amdgcn_update_dpp(0, v, 0x111, 0xf, 0xf, true);  // row_shr:1
    v = (v > t) ? v : t;
    t = __builtin_amdgcn_update_dpp(0, v, 0x112, 0xf, 0xf, true);  // row_shr:2
    v = (v > t) ? v : t;
    t = __builtin_amdgcn_update_dpp(0, v, 0x114, 0xf, 0xf, true);  // row_shr:4
    v = (v > t) ? v : t;
    t = __builtin_amdgcn_update_dpp(0, v, 0x118, 0xf, 0xf, true);  // row_shr:8
    v = (v > t) ? v : t;
    t = __builtin_amdgcn_update_dpp(v, v, 0x142, 0xa, 0xf, false); // row_bcast:15
    v = (v > t) ? v : t;
    t = __builtin_amdgcn_update_dpp(v, v, 0x143, 0xc, 0xf, false); // row_bcast:31
    v = (v > t) ? v : t;
    return __builtin_amdgcn_readlane(v, 63);
}

// Branch-free insert of k into sorted (m1 >= m2 >= m3), 64-bit keys.
__device__ __forceinline__ void insert3(unsigned long long k,
    unsigned long long& m1, unsigned long long& m2, unsigned long long& m3) {
    const bool c1 = k > m1, c2 = k > m2, c3 = k > m3;
    m3 = c3 ? (c2 ? m2 : k) : m3;   // uses old m2
    m2 = c2 ? (c1 ? m1 : k) : m2;   // uses old m1
    m1 = c1 ? k : m1;
}

// Per-tile consume: wait for this tile's two loads (14-t = younger loads +
// stores in the vmcnt FIFO), fence the scheduler (rule #18), then write the
// base output and feed scores into the per-lane top-3 cache.
#define TILE(t, vm) do {                                                     \
    asm volatile("s_waitcnt vmcnt(" #vm ")" ::: "memory");                   \
    __builtin_amdgcn_sched_barrier(0);                                       \
    const int col = (t) * 256 + lane4;                                       \
    vfloat4 ov = av[t] * 1e-7f;                                              \
    __builtin_nontemporal_store(ov, reinterpret_cast<vfloat4*>(orow + col)); \
    float s[4];                                                              \
    {                                                                        \
        _Pragma("clang fp contract(off)")                                    \
        s[0] = fabsf(av[t].x) + nv[t].x * 0.01f;                             \
        s[1] = fabsf(av[t].y) + nv[t].y * 0.01f;                             \
        s[2] = fabsf(av[t].z) + nv[t].z * 0.01f;                             \
        s[3] = fabsf(av[t].w) + nv[t].w * 0.01f;                             \
    }                                                                        \
    _Pragma("unroll")                                                        \
    for (int c = 0; c < 4; ++c) {                                            \
        sc[(t) * 4 + c] = s[c];                                              \
        unsigned long long k =                                               \
            ((unsigned long long)__float_as_uint(s[c]) << 32) |              \
            (unsigned int)(NN - 1 - (col + c));                              \
        insert3(k, m1, m2, m3);                                              \
    }                                                                        \
} while (0)

// Kernel 1: one 64-lane wave per row; 32 scores/lane in registers.
// Exact ordered top-20 per row (score desc, col asc on float-bit ties).
// Writes base output adj*EPS (non-temporal), winners[rg][rank] = col, and
// compacts adj[rg][0..19] into adjhead so kernel2 never re-reads adj.
__global__ __launch_bounds__(256) void mask_topk_rows(
    const float* __restrict__ adj, const float* __restrict__ noise,
    float* __restrict__ out, unsigned short* __restrict__ winners,
    float* __restrict__ adjhead)
{
    const int lane  = threadIdx.x & 63;
    const int wave  = threadIdx.x >> 6;
    const int rg    = (blockIdx.x << 2) + wave;     // 0..16383
    const size_t base = (size_t)rg * NN;
    const float* __restrict__ arow = adj + base;
    const float* __restrict__ nrow = noise + base;
    float* __restrict__ orow = out + base;

    const int lane4 = lane << 2;

    // ---- Issue ALL 16 loads via volatile asm (issue-order pinned) ----
    vfloat4 av[8], nv[8];
    #pragma unroll
    for (int t = 0; t < 8; ++t) {
        asm volatile("global_load_dwordx4 %0, %1, off"
                     : "=v"(av[t]) : "v"(arow + t * 256 + lane4));
        asm volatile("global_load_dwordx4 %0, %1, off"
                     : "=v"(nv[t]) : "v"(nrow + t * 256 + lane4));
    }
    __builtin_amdgcn_sched_barrier(0);

    float sc[32];
    unsigned long long m1 = 0ull, m2 = 0ull, m3 = 0ull;  // sorted top-3 keys

    TILE(0, 14); TILE(1, 13); TILE(2, 12); TILE(3, 11);
    TILE(4, 10); TILE(5,  9); TILE(6,  8); TILE(7,  7);

    // Compact first 20 columns of this row (lanes 0..4 hold cols 0..19 in
    // av[0]) -- kernel2 reads these instead of scattered adj cachelines.
    // 80B/row: rg*20*4 = rg*80 is 16B-aligned.
    if (lane < 5) {
        *reinterpret_cast<vfloat4*>(adjhead + (size_t)rg * KK + lane4) = av[0];
    }

    int cnt = 3;                 // valid entries in the per-lane cache
    unsigned int removed = 0;    // per-lane slot mask of extracted elements
    unsigned int mycol = 0;

    #pragma clang loop unroll(disable)
    for (int pass = 0; pass < KK; ++pass) {
        const int hs = (int)(unsigned int)(m1 >> 32);     // score bits (>=0)
        const int smax = wave_max_i32(hs);                // global max score
        const bool tied = (hs == smax);
        const unsigned long long ball = __ballot(tied);
        unsigned int col;
        bool iwin;
        if (__popcll(ball) == 1) {
            // fast path: unique score owner -- no tie-break reduce needed
            const int wl = __ffsll((long long)ball) - 1;  // SGPR-uniform lane
            const unsigned int wlo = (unsigned int)
                __builtin_amdgcn_readlane((int)(unsigned int)m1, wl);
            col = (NN - 1) - wlo;
            iwin = (lane == wl);
        } else {
            // exact tie on score bits across lanes: pick smallest col
            const int lo = tied ? (int)(unsigned int)m1 : 0;  // 2047-col
            const int tmax = wave_max_i32(lo);
            col = (NN - 1) - (unsigned int)tmax;
            iwin = tied && ((int)(unsigned int)m1 == tmax);
        }
        if (lane == pass) mycol = col;
        if (iwin) {
            const int slot = ((col >> 8) << 2) | (col & 3);
            removed |= (1u << slot);
            m1 = m2; m2 = m3; m3 = 0ull;
            if (--cnt == 0) {
                // rare (~0.3/row): rebuild top-3 of non-removed elements
                m1 = 0ull; m2 = 0ull; m3 = 0ull;
                #pragma unroll
                for (int ss = 0; ss < 32; ++ss) {
                    if (!((removed >> ss) & 1u)) {
                        const int c2 = ((ss >> 2) << 8) + lane4 + (ss & 3);
                        unsigned long long k =
                            ((unsigned long long)__float_as_uint(sc[ss]) << 32) |
                            (unsigned int)(NN - 1 - c2);
                        insert3(k, m1, m2, m3);
                    }
                }
                cnt = 3;
            }
        }
    }

    if (lane < KK) {
        winners[(size_t)rg * KK + lane] = (unsigned short)mycol;
    }
}

// Kernel 2: for each (slice,row,rank): col = winners[...];
// out[slice][col][rank] = adjhead[slice*NN+col][rank]*(1+EPS).
// Duplicate (col,rank) targets write identical values -> benign race.
__global__ __launch_bounds__(256) void mask_boost(
    float* __restrict__ out, const unsigned short* __restrict__ winners,
    const float* __restrict__ adjhead)
{
    const int idx = blockIdx.x * 256 + threadIdx.x;
    if (idx >= NBOOST) return;
    const int rank  = idx % KK;
    const int slice = idx / (KK * NN);
    const int col = winners[idx];
    const size_t wrow = (size_t)slice * NN + col;
    const float v = adjhead[wrow * KK + rank];
    out[wrow * NN + rank] = v * (1.0f + 1e-7f);
}

extern "C" void kernel_launch(void* const* d_in, const int* in_sizes, int n_in,
                              void* d_out, int out_size, void* d_ws, size_t ws_size,
                              hipStream_t stream) {
    const float* adj   = (const float*)d_in[0];
    const float* noise = (const float*)d_in[1];
    float* out = (float*)d_out;
    unsigned short* winners = (unsigned short*)d_ws;            // 640 KiB
    float* adjhead = (float*)((char*)d_ws + (size_t)NROWS * KK * sizeof(unsigned short));
    // adjhead: 16384*20*4B = 1.25 MiB (total ws use < 2 MiB)

    mask_topk_rows<<<NROWS / 4, 256, 0, stream>>>(adj, noise, out, winners, adjhead);
    mask_boost<<<(NBOOST + 255) / 256, 256, 0, stream>>>(out, winners, adjhead);
}